// Round 2
// baseline (420.553 us; speedup 1.0000x reference)
//
#include <hip/hip_runtime.h>

typedef unsigned short u16;
typedef u16 u16x8 __attribute__((ext_vector_type(8)));
typedef __bf16 bf16x8 __attribute__((ext_vector_type(8)));
typedef float f32x4 __attribute__((ext_vector_type(4)));

#define HB   256    // H
#define NND  127    // nodes per tree
#define BT   512    // trees (batch)
#define KE   300    // E
#define KEP  320    // E padded to 32-multiple
#define VV   50000  // vocab
#define QQ   10     // Q

__device__ __forceinline__ u16 f2bf(float f) {
    unsigned int u = __builtin_bit_cast(unsigned int, f);
    u += 0x7FFFu + ((u >> 16) & 1u);          // RNE
    return (u16)(u >> 16);
}
__device__ __forceinline__ float bf2f(u16 h) {
    unsigned int u = ((unsigned int)h) << 16;
    return __builtin_bit_cast(float, u);
}
__device__ __forceinline__ float sigm(float x) { return 1.f / (1.f + __expf(-x)); }

// ---------- qD = q @ D.T  (QQ x 768), fp32 ----------
__global__ __launch_bounds__(256) void k_qd(const float* __restrict__ q,
                                            const float* __restrict__ D,
                                            float* __restrict__ qD) {
    int i = blockIdx.x * 256 + threadIdx.x;
    if (i >= QQ * 768) return;
    int qi = i / 768, col = i - qi * 768;
    const float* qr = q + qi * HB;
    const float* dr = D + col * HB;
    float s = 0.f;
    for (int k = 0; k < HB; ++k) s += qr[k] * dr[k];
    qD[i] = s;
}

// ---------- NT GEMM with fp32->bf16 stage-convert ----------
// C[M,N] = A[M,K] * B[N,K]^T ; A,B fp32 row-major (row stride = K actual).
// Kp = K rounded up to 32; zero-fill k in [K, Kp).
// optional A-row map: global_row = (r>>cnlog2)*127 + cstart + (r & ((1<<cnlog2)-1))
template <bool STORE_BF16>
__global__ __launch_bounds__(256) void k_gemm(const float* __restrict__ A,
                                              const float* __restrict__ B,
                                              void* __restrict__ C,
                                              int M, int N, int K, int Kp,
                                              int map_cnlog2, int map_cstart) {
    __shared__ u16 As[128 * 32];
    __shared__ u16 Bs[128 * 32];
    int row0 = blockIdx.y * 128, col0 = blockIdx.x * 128;
    int t = threadIdx.x;
    int lane = t & 63, wave = t >> 6;
    int wr = wave >> 1, wc = wave & 1;

    // staging: thread t covers tile row sr, 16-elem half shf
    int sr = t >> 1, shf = (t & 1) * 16;
    int ga = row0 + sr; if (ga > M - 1) ga = M - 1;
    if (map_cnlog2 >= 0) {
        int bt = ga >> map_cnlog2;
        int of = ga & ((1 << map_cnlog2) - 1);
        ga = bt * NND + map_cstart + of;
    }
    const float* arow = A + (long)ga * K;
    const float* brow = B + (long)(col0 + sr) * K;
    u16* adst = &As[sr * 32 + shf];
    u16* bdst = &Bs[sr * 32 + shf];

    f32x4 acc[4][4];
#pragma unroll
    for (int m = 0; m < 4; ++m)
#pragma unroll
        for (int n = 0; n < 4; ++n) acc[m][n] = f32x4{0.f, 0.f, 0.f, 0.f};

    int nk = Kp >> 5;
    for (int kt = 0; kt < nk; ++kt) {
        int kb = kt * 32 + shf;
        u16x8 a0, a1, b0, b1;
        if (kb + 16 <= K) {
#pragma unroll
            for (int e = 0; e < 8; ++e) {
                a0[e] = f2bf(arow[kb + e]);     a1[e] = f2bf(arow[kb + 8 + e]);
                b0[e] = f2bf(brow[kb + e]);     b1[e] = f2bf(brow[kb + 8 + e]);
            }
        } else {
#pragma unroll
            for (int e = 0; e < 8; ++e) {
                a0[e] = (kb + e < K)     ? f2bf(arow[kb + e])     : (u16)0;
                a1[e] = (kb + 8 + e < K) ? f2bf(arow[kb + 8 + e]) : (u16)0;
                b0[e] = (kb + e < K)     ? f2bf(brow[kb + e])     : (u16)0;
                b1[e] = (kb + 8 + e < K) ? f2bf(brow[kb + 8 + e]) : (u16)0;
            }
        }
        *(u16x8*)adst = a0; *(u16x8*)(adst + 8) = a1;
        *(u16x8*)bdst = b0; *(u16x8*)(bdst + 8) = b1;
        __syncthreads();
        bf16x8 af[4], bfr[4];
        int arl = wr * 64 + (lane & 15);
        int brl = wc * 64 + (lane & 15);
        int kk = (lane >> 4) * 8;
#pragma unroll
        for (int m = 0; m < 4; ++m)
            af[m] = *(const bf16x8*)&As[(arl + m * 16) * 32 + kk];
#pragma unroll
        for (int n = 0; n < 4; ++n)
            bfr[n] = *(const bf16x8*)&Bs[(brl + n * 16) * 32 + kk];
#pragma unroll
        for (int m = 0; m < 4; ++m)
#pragma unroll
            for (int n = 0; n < 4; ++n)
                acc[m][n] = __builtin_amdgcn_mfma_f32_16x16x32_bf16(af[m], bfr[n], acc[m][n], 0, 0, 0);
        __syncthreads();
    }

    int crow = row0 + wr * 64 + (lane >> 4) * 4;
    int ccol = col0 + wc * 64 + (lane & 15);
#pragma unroll
    for (int m = 0; m < 4; ++m) {
#pragma unroll
        for (int n = 0; n < 4; ++n) {
#pragma unroll
            for (int j = 0; j < 4; ++j) {
                int r = crow + m * 16 + j;
                int c = ccol + n * 16;
                if (r < M) {
                    if (STORE_BF16) ((u16*)C)[(long)r * N + c] = f2bf(acc[m][n][j]);
                    else            ((float*)C)[(long)r * N + c] = acc[m][n][j];
                }
            }
        }
    }
}

// ---------- leaves: h = tanh(sigmoid(i0)*tanh(u0)), i0/u0 = vWiu[tok] + qD[Q-1,iu] + biu ----------
__global__ __launch_bounds__(256) void k_leaf(const int* __restrict__ tok,
                                              const u16* __restrict__ vW,
                                              const float* __restrict__ qD,
                                              const float* __restrict__ b,
                                              float* __restrict__ h) {
    int leaf = blockIdx.x, j = threadIdx.x;
    int bt = leaf >> 6, li = leaf & 63;        // 64 leaves per tree
    int row = bt * NND + 63 + li;
    long vwb = (long)tok[row] * 768;
    float ii = bf2f(vW[vwb + 256 + j]) + qD[9 * 768 + 256 + j] + b[256 + j];
    float uu = bf2f(vW[vwb + 512 + j]) + qD[9 * 768 + 512 + j] + b[512 + j];
    h[(long)row * HB + j] = tanhf(sigm(ii) * tanhf(uu));
}

// ---------- per-level child-sum (compact parent order), fp32 ----------
__global__ __launch_bounds__(256) void k_hsum(const float* __restrict__ h,
                                              float* __restrict__ hs,
                                              int pstart, int pnl) {
    int pi = blockIdx.x, j = threadIdx.x;
    int bt = pi >> pnl, po = pi & ((1 << pnl) - 1);
    int pl = pstart + po;
    long c1 = (long)(bt * NND + 2 * pl + 1) * HB;
    hs[(long)pi * HB + j] = h[c1 + j] + h[c1 + HB + j];
}

// ---------- per-level node update ----------
__global__ __launch_bounds__(256) void k_update(const int* __restrict__ tok,
                                                const int* __restrict__ dep,
                                                const u16* __restrict__ vW,
                                                const float* __restrict__ qD,
                                                const float* __restrict__ b,
                                                const float* __restrict__ gf,
                                                const float* __restrict__ gs,
                                                float* __restrict__ h,
                                                int pstart, int pnl) {
    int pi = blockIdx.x, j = threadIdx.x;
    int bt = pi >> pnl, po = pi & ((1 << pnl) - 1);
    int pl = pstart + po;
    int gp  = bt * NND + pl;
    int gc1 = bt * NND + 2 * pl + 1, gc2 = gc1 + 1;
    int cc1 = (bt << (pnl + 1)) + 2 * po, cc2 = cc1 + 1;  // rows of gf
    long vwb = (long)tok[gp] * 768;
    int d1 = dep[gc1] * 768, d2 = dep[gc2] * 768;
    float xf = bf2f(vW[vwb + j]) + b[j];
    float f1 = sigm(xf + gf[(long)cc1 * HB + j] + qD[d1 + j]);
    float f2 = sigm(xf + gf[(long)cc2 * HB + j] + qD[d2 + j]);
    float ii = bf2f(vW[vwb + 256 + j]) + gs[(long)pi * 512 + j]
             + qD[d1 + 256 + j] + qD[d2 + 256 + j] + b[256 + j];
    float uu = bf2f(vW[vwb + 512 + j]) + gs[(long)pi * 512 + 256 + j]
             + qD[d1 + 512 + j] + qD[d2 + 512 + j] + b[512 + j];
    float h1 = h[(long)gc1 * HB + j];
    float h2 = h[(long)gc2 * HB + j];
    float hn = tanhf(sigm(ii) * tanhf(uu) + f1 * h1 + f2 * h2);
    h[(long)gp * HB + j] = hn;
}

// ---------- gather roots to output (fp32) ----------
__global__ __launch_bounds__(256) void k_out(const float* __restrict__ h,
                                             float* __restrict__ out) {
    int bt = blockIdx.x, j = threadIdx.x;
    out[bt * HB + j] = h[(long)bt * NND * HB + j];
}

extern "C" void kernel_launch(void* const* d_in, const int* in_sizes, int n_in,
                              void* d_out, int out_size, void* d_ws, size_t ws_size,
                              hipStream_t stream) {
    const int*   tok = (const int*)d_in[0];
    const int*   dep = (const int*)d_in[1];
    const float* vec = (const float*)d_in[2];
    const float* q   = (const float*)d_in[3];
    const float* W   = (const float*)d_in[4];
    const float* U   = (const float*)d_in[5];
    const float* D   = (const float*)d_in[6];
    const float* b   = (const float*)d_in[7];

    char* ws = (char*)d_ws;
    size_t off = 0;
    auto alloc = [&](size_t bytes) {
        void* p = ws + off;
        off += (bytes + 255) & ~(size_t)255;
        return p;
    };
    float* qD = (float*)alloc((size_t)QQ * 768 * 4);
    u16*   vW = (u16*)alloc((size_t)VV * 768 * 2);
    float* h  = (float*)alloc((size_t)BT * NND * HB * 4);
    float* hs = (float*)alloc((size_t)BT * 32 * HB * 4);
    float* gf = (float*)alloc((size_t)BT * 64 * HB * 4);
    float* gs = (float*)alloc((size_t)BT * 32 * 512 * 4);
    if (ws_size < off) return;  // ~227 MiB needed; zero output signals ws too small

    k_qd<<<30, 256, 0, stream>>>(q, D, qD);

    // vW = (idx2vec @ W.T) as bf16, vocab-wide
    k_gemm<true><<<dim3(6, (VV + 127) / 128), 256, 0, stream>>>(
        vec, W, vW, VV, 768, KE, KEP, -1, 0);

    k_leaf<<<BT * 64, 256, 0, stream>>>(tok, vW, qD, b, h);

    for (int lv = 1; lv <= 6; ++lv) {
        int pnl = 6 - lv;              // log2(parents per tree)
        int pn = 1 << pnl;
        int pstart = pn - 1;
        int cnl = pnl + 1;             // log2(children per tree)
        int cstart = (1 << cnl) - 1;
        int npT = BT * pn, ncT = BT * (1 << cnl);
        k_hsum<<<npT, 256, 0, stream>>>(h, hs, pstart, pnl);
        // gf[children, H] = h_child @ Uf.T   (A rows mapped into the tree layout)
        k_gemm<false><<<dim3(2, ncT / 128), 256, 0, stream>>>(
            h, U, gf, ncT, 256, HB, HB, cnl, cstart);
        // gs[parents, 2H] = (h_c1 + h_c2) @ Uiu.T
        k_gemm<false><<<dim3(4, npT / 128), 256, 0, stream>>>(
            hs, U + 256 * HB, gs, npT, 512, HB, HB, -1, 0);
        k_update<<<npT, 256, 0, stream>>>(tok, dep, vW, qD, b, gf, gs, h, pstart, pnl);
    }

    k_out<<<BT, 256, 0, stream>>>(h, (float*)d_out);
}

// Round 3
// 318.541 us; speedup vs baseline: 1.3202x; 1.3202x over previous
//
#include <hip/hip_runtime.h>

typedef unsigned short u16;
typedef u16 u16x8 __attribute__((ext_vector_type(8)));
typedef __bf16 bf16x8 __attribute__((ext_vector_type(8)));
typedef float f32x4 __attribute__((ext_vector_type(4)));

#define HB   256    // H
#define NND  127    // nodes per tree
#define BT   512    // trees (batch)
#define KE   300    // E
#define KEP  320    // E padded to 32-multiple
#define VV   50000  // vocab
#define QQ   10     // Q

#define AS1 __attribute__((address_space(1)))
#define AS3 __attribute__((address_space(3)))

__device__ __forceinline__ u16 f2bf(float f) {
    unsigned int u = __builtin_bit_cast(unsigned int, f);
    u += 0x7FFFu + ((u >> 16) & 1u);          // RNE
    return (u16)(u >> 16);
}
__device__ __forceinline__ float bf2f(u16 h) {
    unsigned int u = ((unsigned int)h) << 16;
    return __builtin_bit_cast(float, u);
}
__device__ __forceinline__ float sigm(float x) { return 1.f / (1.f + __expf(-x)); }

__device__ __forceinline__ void glds16(const u16* g, u16* l) {
    __builtin_amdgcn_global_load_lds((const AS1 void*)g, (AS3 void*)l, 16, 0, 0);
}

// ---------- fp32 -> bf16 convert with K -> Kp zero padding, u16x8 stores ----------
__global__ __launch_bounds__(256) void k_conv(const float* __restrict__ src,
                                              u16* __restrict__ dst,
                                              int rows, int K, int Kp) {
    int i = blockIdx.x * 256 + threadIdx.x;   // one 8-elem chunk per thread
    int nch = Kp >> 3;
    if (i >= rows * nch) return;
    int r = i / nch, c = (i - r * nch) * 8;
    const float* s = src + (long)r * K + c;
    u16x8 o;
#pragma unroll
    for (int e = 0; e < 8; ++e) o[e] = (c + e < K) ? f2bf(s[e]) : (u16)0;
    *(u16x8*)(dst + (long)i * 8) = o;
}

// ---------- qD = q @ D.T  (QQ x 768), fp32 ----------
__global__ __launch_bounds__(256) void k_qd(const float* __restrict__ q,
                                            const float* __restrict__ D,
                                            float* __restrict__ qD) {
    int i = blockIdx.x * 256 + threadIdx.x;
    if (i >= QQ * 768) return;
    int qi = i / 768, col = i - qi * 768;
    const float* qr = q + qi * HB;
    const float* dr = D + col * HB;
    float s = 0.f;
    for (int k = 0; k < HB; ++k) s += qr[k] * dr[k];
    qD[i] = s;
}

// ---------- bf16 NT GEMM, m97 structure: global_load_lds(16B), 128x128 tile ----------
// C[M,N] = A[M,K] * B[N,K]^T ; A,B bf16 row-major, K % 32 == 0, N % 128 == 0.
// optional A-row map: global_row = (r>>cnlog2)*127 + cstart + (r & ((1<<cnlog2)-1))
template <bool STORE_BF16>
__global__ __launch_bounds__(256) void k_gemm(const u16* __restrict__ A,
                                              const u16* __restrict__ B,
                                              void* __restrict__ C,
                                              int M, int N, int K,
                                              int map_cnlog2, int map_cstart) {
    __shared__ u16 As[128 * 32];
    __shared__ u16 Bs[128 * 32];

    // bijective XCD-chunked swizzle (m204) on linear bid, x-inner
    int nwg = gridDim.x * gridDim.y;
    int orig = blockIdx.y * gridDim.x + blockIdx.x;
    int qq = nwg >> 3, rr = nwg & 7;
    int xcd = orig & 7, cidx = orig >> 3;
    int wg = (xcd < rr ? xcd * (qq + 1) : rr * (qq + 1) + (xcd - rr) * qq) + cidx;
    int bx = wg % gridDim.x, by = wg / gridDim.x;
    int row0 = by * 128, col0 = bx * 128;

    int t = threadIdx.x, lane = t & 63, w = t >> 6;
    int wr = w >> 1, wc = w & 1;

    // staging geometry: per wave-issue, 64 lanes x 16B = 16 rows x 32 u16
    int cof = (lane & 3) * 8;            // u16 col offset
    int rin = lane >> 2;                 // 0..15 row within issue
    int ar0 = row0 + w * 32 + rin;
    int ar1 = ar0 + 16;
    auto mapfn = [&](int r) {
        if (r > M - 1) r = M - 1;
        if (map_cnlog2 >= 0) {
            int bt = r >> map_cnlog2;
            int of = r & ((1 << map_cnlog2) - 1);
            r = bt * NND + map_cstart + of;
        }
        return r;
    };
    const u16* aS0 = A + (long)mapfn(ar0) * K + cof;
    const u16* aS1 = A + (long)mapfn(ar1) * K + cof;
    const u16* bS0 = B + (long)(col0 + w * 32 + rin) * K + cof;
    const u16* bS1 = bS0 + 16L * K;
    u16* aD0 = As + (w * 32) * 32;
    u16* aD1 = As + (w * 32 + 16) * 32;
    u16* bD0 = Bs + (w * 32) * 32;
    u16* bD1 = Bs + (w * 32 + 16) * 32;

    f32x4 acc[4][4];
#pragma unroll
    for (int m = 0; m < 4; ++m)
#pragma unroll
        for (int n = 0; n < 4; ++n) acc[m][n] = f32x4{0.f, 0.f, 0.f, 0.f};

    int arl = wr * 64 + (lane & 15);
    int brl = wc * 64 + (lane & 15);
    int kk = (lane >> 4) * 8;

    int nk = K >> 5;
    for (int kt = 0; kt < nk; ++kt) {
        int ko = kt * 32;
        glds16(aS0 + ko, aD0);
        glds16(aS1 + ko, aD1);
        glds16(bS0 + ko, bD0);
        glds16(bS1 + ko, bD1);
        __syncthreads();                 // drains vmcnt -> LDS ready
        bf16x8 af[4], bfr[4];
#pragma unroll
        for (int m = 0; m < 4; ++m)
            af[m] = *(const bf16x8*)&As[(arl + m * 16) * 32 + kk];
#pragma unroll
        for (int n = 0; n < 4; ++n)
            bfr[n] = *(const bf16x8*)&Bs[(brl + n * 16) * 32 + kk];
#pragma unroll
        for (int m = 0; m < 4; ++m)
#pragma unroll
            for (int n = 0; n < 4; ++n)
                acc[m][n] = __builtin_amdgcn_mfma_f32_16x16x32_bf16(af[m], bfr[n], acc[m][n], 0, 0, 0);
        __syncthreads();
    }

    int crow = row0 + wr * 64 + (lane >> 4) * 4;
    int ccol = col0 + wc * 64 + (lane & 15);
#pragma unroll
    for (int m = 0; m < 4; ++m) {
#pragma unroll
        for (int n = 0; n < 4; ++n) {
#pragma unroll
            for (int j = 0; j < 4; ++j) {
                int r = crow + m * 16 + j;
                int c = ccol + n * 16;
                if (r < M) {
                    if (STORE_BF16) ((u16*)C)[(long)r * N + c] = f2bf(acc[m][n][j]);
                    else            ((float*)C)[(long)r * N + c] = acc[m][n][j];
                }
            }
        }
    }
}

// ---------- leaves: h = tanh(sigmoid(i0)*tanh(u0)) ----------
__global__ __launch_bounds__(256) void k_leaf(const int* __restrict__ tok,
                                              const u16* __restrict__ vW,
                                              const float* __restrict__ qD,
                                              const float* __restrict__ b,
                                              u16* __restrict__ h) {
    int leaf = blockIdx.x, j = threadIdx.x;
    int bt = leaf >> 6, li = leaf & 63;        // 64 leaves per tree
    int row = bt * NND + 63 + li;
    long vwb = (long)tok[row] * 768;
    float ii = bf2f(vW[vwb + 256 + j]) + qD[9 * 768 + 256 + j] + b[256 + j];
    float uu = bf2f(vW[vwb + 512 + j]) + qD[9 * 768 + 512 + j] + b[512 + j];
    h[(long)row * HB + j] = f2bf(tanhf(sigm(ii) * tanhf(uu)));
}

// ---------- per-level child-sum (compact parent order), bf16 ----------
__global__ __launch_bounds__(256) void k_hsum(const u16* __restrict__ h,
                                              u16* __restrict__ hs,
                                              int pstart, int pnl) {
    int pi = blockIdx.x, j = threadIdx.x;
    int bt = pi >> pnl, po = pi & ((1 << pnl) - 1);
    int pl = pstart + po;
    long c1 = (long)(bt * NND + 2 * pl + 1) * HB;
    hs[(long)pi * HB + j] = f2bf(bf2f(h[c1 + j]) + bf2f(h[c1 + HB + j]));
}

// ---------- per-level node update; lv==6 writes fp32 roots to out ----------
__global__ __launch_bounds__(256) void k_update(const int* __restrict__ tok,
                                                const int* __restrict__ dep,
                                                const u16* __restrict__ vW,
                                                const float* __restrict__ qD,
                                                const float* __restrict__ b,
                                                const float* __restrict__ gf,
                                                const float* __restrict__ gs,
                                                u16* __restrict__ h,
                                                float* __restrict__ out,
                                                int pstart, int pnl) {
    int pi = blockIdx.x, j = threadIdx.x;
    int bt = pi >> pnl, po = pi & ((1 << pnl) - 1);
    int pl = pstart + po;
    int gp  = bt * NND + pl;
    int gc1 = bt * NND + 2 * pl + 1, gc2 = gc1 + 1;
    int cc1 = (bt << (pnl + 1)) + 2 * po, cc2 = cc1 + 1;  // rows of gf
    long vwb = (long)tok[gp] * 768;
    int d1 = dep[gc1] * 768, d2 = dep[gc2] * 768;
    float xf = bf2f(vW[vwb + j]) + b[j];
    float f1 = sigm(xf + gf[(long)cc1 * HB + j] + qD[d1 + j]);
    float f2 = sigm(xf + gf[(long)cc2 * HB + j] + qD[d2 + j]);
    float ii = bf2f(vW[vwb + 256 + j]) + gs[(long)pi * 512 + j]
             + qD[d1 + 256 + j] + qD[d2 + 256 + j] + b[256 + j];
    float uu = bf2f(vW[vwb + 512 + j]) + gs[(long)pi * 512 + 256 + j]
             + qD[d1 + 512 + j] + qD[d2 + 512 + j] + b[512 + j];
    float h1 = bf2f(h[(long)gc1 * HB + j]);
    float h2 = bf2f(h[(long)gc2 * HB + j]);
    float hn = tanhf(sigm(ii) * tanhf(uu) + f1 * h1 + f2 * h2);
    if (out) out[(long)pi * HB + j] = hn;          // lv6: pi == bt, fp32 output
    else     h[(long)gp * HB + j] = f2bf(hn);
}

extern "C" void kernel_launch(void* const* d_in, const int* in_sizes, int n_in,
                              void* d_out, int out_size, void* d_ws, size_t ws_size,
                              hipStream_t stream) {
    const int*   tok = (const int*)d_in[0];
    const int*   dep = (const int*)d_in[1];
    const float* vec = (const float*)d_in[2];
    const float* q   = (const float*)d_in[3];
    const float* W   = (const float*)d_in[4];
    const float* U   = (const float*)d_in[5];
    const float* D   = (const float*)d_in[6];
    const float* b   = (const float*)d_in[7];

    char* ws = (char*)d_ws;
    size_t off = 0;
    auto alloc = [&](size_t bytes) {
        void* p = ws + off;
        off += (bytes + 255) & ~(size_t)255;
        return p;
    };
    float* qD = (float*)alloc((size_t)QQ * 768 * 4);
    u16*   vb = (u16*)alloc((size_t)VV * KEP * 2);
    u16*   Wb = (u16*)alloc((size_t)768 * KEP * 2);
    u16*   Ub = (u16*)alloc((size_t)768 * HB * 2);
    u16*   vW = (u16*)alloc((size_t)VV * 768 * 2);
    u16*   h  = (u16*)alloc((size_t)BT * NND * HB * 2);
    u16*   hs = (u16*)alloc((size_t)BT * 32 * HB * 2);
    float* gf = (float*)alloc((size_t)BT * 64 * HB * 4);
    float* gs = (float*)alloc((size_t)BT * 32 * 512 * 4);
    if (ws_size < off) return;  // ~210 MiB needed; zero output signals ws too small

    k_conv<<<(VV * (KEP / 8) + 255) / 256, 256, 0, stream>>>(vec, vb, VV, KE, KEP);
    k_conv<<<(768 * (KEP / 8) + 255) / 256, 256, 0, stream>>>(W, Wb, 768, KE, KEP);
    k_conv<<<(768 * (HB / 8) + 255) / 256, 256, 0, stream>>>(U, Ub, 768, HB, HB);
    k_qd<<<30, 256, 0, stream>>>(q, D, qD);

    // vW = (idx2vec @ W.T) as bf16, vocab-wide
    k_gemm<true><<<dim3(6, (VV + 127) / 128), 256, 0, stream>>>(
        vb, Wb, vW, VV, 768, KEP, -1, 0);

    k_leaf<<<BT * 64, 256, 0, stream>>>(tok, vW, qD, b, h);

    for (int lv = 1; lv <= 6; ++lv) {
        int pnl = 6 - lv;              // log2(parents per tree)
        int pn = 1 << pnl;
        int pstart = pn - 1;
        int cnl = pnl + 1;             // log2(children per tree)
        int cstart = (1 << cnl) - 1;
        int npT = BT * pn, ncT = BT * (1 << cnl);
        k_hsum<<<npT, 256, 0, stream>>>(h, hs, pstart, pnl);
        // gf[children, H] = h_child @ Uf.T   (A rows mapped into the tree layout)
        k_gemm<false><<<dim3(2, ncT / 128), 256, 0, stream>>>(
            h, Ub, gf, ncT, 256, HB, cnl, cstart);
        // gs[parents, 2H] = (h_c1 + h_c2) @ Uiu.T
        k_gemm<false><<<dim3(4, npT / 128), 256, 0, stream>>>(
            hs, Ub + 256 * HB, gs, npT, 512, HB, -1, 0);
        k_update<<<npT, 256, 0, stream>>>(tok, dep, vW, qD, b, gf, gs, h,
                                          (lv == 6) ? (float*)d_out : nullptr,
                                          pstart, pnl);
    }
}

// Round 4
// 246.555 us; speedup vs baseline: 1.7057x; 1.2920x over previous
//
#include <hip/hip_runtime.h>

typedef unsigned short u16;
typedef u16 u16x8 __attribute__((ext_vector_type(8)));
typedef __bf16 bf16x8 __attribute__((ext_vector_type(8)));
typedef float f32x4 __attribute__((ext_vector_type(4)));

#define HB   256    // H
#define NND  127    // nodes per tree
#define BT   512    // trees (batch)
#define KE   300    // E
#define KEP  320    // E padded to 32-multiple
#define VV   50000  // vocab
#define QQ   10     // Q

#define AS1 __attribute__((address_space(1)))
#define AS3 __attribute__((address_space(3)))

__device__ __forceinline__ u16 f2bf(float f) {
    unsigned int u = __builtin_bit_cast(unsigned int, f);
    u += 0x7FFFu + ((u >> 16) & 1u);          // RNE
    return (u16)(u >> 16);
}
__device__ __forceinline__ float bf2f(u16 h) {
    unsigned int u = ((unsigned int)h) << 16;
    return __builtin_bit_cast(float, u);
}
__device__ __forceinline__ float sigm(float x) { return 1.f / (1.f + __expf(-x)); }

__device__ __forceinline__ void glds16(const u16* g, u16* l) {
    __builtin_amdgcn_global_load_lds((const AS1 void*)g, (AS3 void*)l, 16, 0, 0);
}

// ---------- fp32 -> bf16 convert with K -> Kp zero padding, u16x8 stores ----------
__global__ __launch_bounds__(256) void k_conv(const float* __restrict__ src,
                                              u16* __restrict__ dst,
                                              int rows, int K, int Kp) {
    int i = blockIdx.x * 256 + threadIdx.x;   // one 8-elem chunk per thread
    int nch = Kp >> 3;
    if (i >= rows * nch) return;
    int r = i / nch, c = (i - r * nch) * 8;
    const float* s = src + (long)r * K + c;
    u16x8 o;
#pragma unroll
    for (int e = 0; e < 8; ++e) o[e] = (c + e < K) ? f2bf(s[e]) : (u16)0;
    *(u16x8*)(dst + (long)i * 8) = o;
}

// ---------- qD = q @ D.T  (QQ x 768), fp32 ----------
__global__ __launch_bounds__(256) void k_qd(const float* __restrict__ q,
                                            const float* __restrict__ D,
                                            float* __restrict__ qD) {
    int i = blockIdx.x * 256 + threadIdx.x;
    if (i >= QQ * 768) return;
    int qi = i / 768, col = i - qi * 768;
    const float* qr = q + qi * HB;
    const float* dr = D + col * HB;
    float s = 0.f;
    for (int k = 0; k < HB; ++k) s += qr[k] * dr[k];
    qD[i] = s;
}

// ---------- bf16 NT GEMM, m97 structure: global_load_lds(16B), 128x128 tile ----------
// C[M,N] = A[M,K] * B[N,K]^T ; A,B bf16 row-major, K % 32 == 0, N % 128 == 0.
// optional A-row map: global_row = (r>>cnlog2)*127 + cstart + (r & ((1<<cnlog2)-1))
template <bool STORE_BF16>
__global__ __launch_bounds__(256) void k_gemm(const u16* __restrict__ A,
                                              const u16* __restrict__ B,
                                              void* __restrict__ C,
                                              int M, int N, int K,
                                              int map_cnlog2, int map_cstart) {
    __shared__ u16 As[128 * 32];
    __shared__ u16 Bs[128 * 32];

    // bijective XCD-chunked swizzle (m204) on linear bid, x-inner
    int nwg = gridDim.x * gridDim.y;
    int orig = blockIdx.y * gridDim.x + blockIdx.x;
    int qq = nwg >> 3, rr = nwg & 7;
    int xcd = orig & 7, cidx = orig >> 3;
    int wg = (xcd < rr ? xcd * (qq + 1) : rr * (qq + 1) + (xcd - rr) * qq) + cidx;
    int bx = wg % gridDim.x, by = wg / gridDim.x;
    int row0 = by * 128, col0 = bx * 128;

    int t = threadIdx.x, lane = t & 63, w = t >> 6;
    int wr = w >> 1, wc = w & 1;

    // staging geometry: per wave-issue, 64 lanes x 16B = 16 rows x 32 u16
    int cof = (lane & 3) * 8;            // u16 col offset
    int rin = lane >> 2;                 // 0..15 row within issue
    int ar0 = row0 + w * 32 + rin;
    int ar1 = ar0 + 16;
    auto mapfn = [&](int r) {
        if (r > M - 1) r = M - 1;
        if (map_cnlog2 >= 0) {
            int bt = r >> map_cnlog2;
            int of = r & ((1 << map_cnlog2) - 1);
            r = bt * NND + map_cstart + of;
        }
        return r;
    };
    const u16* aS0 = A + (long)mapfn(ar0) * K + cof;
    const u16* aS1 = A + (long)mapfn(ar1) * K + cof;
    const u16* bS0 = B + (long)(col0 + w * 32 + rin) * K + cof;
    const u16* bS1 = bS0 + 16L * K;
    u16* aD0 = As + (w * 32) * 32;
    u16* aD1 = As + (w * 32 + 16) * 32;
    u16* bD0 = Bs + (w * 32) * 32;
    u16* bD1 = Bs + (w * 32 + 16) * 32;

    f32x4 acc[4][4];
#pragma unroll
    for (int m = 0; m < 4; ++m)
#pragma unroll
        for (int n = 0; n < 4; ++n) acc[m][n] = f32x4{0.f, 0.f, 0.f, 0.f};

    int arl = wr * 64 + (lane & 15);
    int brl = wc * 64 + (lane & 15);
    int kk = (lane >> 4) * 8;

    int nk = K >> 5;
    for (int kt = 0; kt < nk; ++kt) {
        int ko = kt * 32;
        glds16(aS0 + ko, aD0);
        glds16(aS1 + ko, aD1);
        glds16(bS0 + ko, bD0);
        glds16(bS1 + ko, bD1);
        __syncthreads();                 // drains vmcnt -> LDS ready
        bf16x8 af[4], bfr[4];
#pragma unroll
        for (int m = 0; m < 4; ++m)
            af[m] = *(const bf16x8*)&As[(arl + m * 16) * 32 + kk];
#pragma unroll
        for (int n = 0; n < 4; ++n)
            bfr[n] = *(const bf16x8*)&Bs[(brl + n * 16) * 32 + kk];
#pragma unroll
        for (int m = 0; m < 4; ++m)
#pragma unroll
            for (int n = 0; n < 4; ++n)
                acc[m][n] = __builtin_amdgcn_mfma_f32_16x16x32_bf16(af[m], bfr[n], acc[m][n], 0, 0, 0);
        __syncthreads();
    }

    int crow = row0 + wr * 64 + (lane >> 4) * 4;
    int ccol = col0 + wc * 64 + (lane & 15);
#pragma unroll
    for (int m = 0; m < 4; ++m) {
#pragma unroll
        for (int n = 0; n < 4; ++n) {
#pragma unroll
            for (int j = 0; j < 4; ++j) {
                int r = crow + m * 16 + j;
                int c = ccol + n * 16;
                if (r < M) {
                    if (STORE_BF16) ((u16*)C)[(long)r * N + c] = f2bf(acc[m][n][j]);
                    else            ((float*)C)[(long)r * N + c] = acc[m][n][j];
                }
            }
        }
    }
}

// ---------- leaves: h = tanh(sigmoid(i0)*tanh(u0)) ----------
__global__ __launch_bounds__(256) void k_leaf(const int* __restrict__ tok,
                                              const u16* __restrict__ vW,
                                              const float* __restrict__ qD,
                                              const float* __restrict__ b,
                                              u16* __restrict__ h) {
    int leaf = blockIdx.x, j = threadIdx.x;
    int bt = leaf >> 6, li = leaf & 63;        // 64 leaves per tree
    int row = bt * NND + 63 + li;
    long vwb = (long)tok[row] * 768;
    float ii = bf2f(vW[vwb + 256 + j]) + qD[9 * 768 + 256 + j] + b[256 + j];
    float uu = bf2f(vW[vwb + 512 + j]) + qD[9 * 768 + 512 + j] + b[512 + j];
    h[(long)row * HB + j] = f2bf(tanhf(sigm(ii) * tanhf(uu)));
}

// ---------- per-level node update reading merged g = h_child @ U.T (bf16) ----------
// g row layout per child c (compact level order): [0:256]=f-part, [256:512]=i, [512:768]=u
__global__ __launch_bounds__(256) void k_update(const int* __restrict__ tok,
                                                const int* __restrict__ dep,
                                                const u16* __restrict__ vW,
                                                const float* __restrict__ qD,
                                                const float* __restrict__ b,
                                                const u16* __restrict__ g,
                                                u16* __restrict__ h,
                                                float* __restrict__ out,
                                                int pstart, int pnl) {
    int pi = blockIdx.x, j = threadIdx.x;
    int bt = pi >> pnl, po = pi & ((1 << pnl) - 1);
    int pl = pstart + po;
    int gp  = bt * NND + pl;
    int gc1 = bt * NND + 2 * pl + 1, gc2 = gc1 + 1;
    long cc1 = (long)((bt << (pnl + 1)) + 2 * po) * 768;  // g rows of the two children
    long cc2 = cc1 + 768;
    long vwb = (long)tok[gp] * 768;
    int d1 = dep[gc1] * 768, d2 = dep[gc2] * 768;
    float xf = bf2f(vW[vwb + j]) + b[j];
    float f1 = sigm(xf + bf2f(g[cc1 + j]) + qD[d1 + j]);
    float f2 = sigm(xf + bf2f(g[cc2 + j]) + qD[d2 + j]);
    float ii = bf2f(vW[vwb + 256 + j]) + bf2f(g[cc1 + 256 + j]) + bf2f(g[cc2 + 256 + j])
             + qD[d1 + 256 + j] + qD[d2 + 256 + j] + b[256 + j];
    float uu = bf2f(vW[vwb + 512 + j]) + bf2f(g[cc1 + 512 + j]) + bf2f(g[cc2 + 512 + j])
             + qD[d1 + 512 + j] + qD[d2 + 512 + j] + b[512 + j];
    float h1 = bf2f(h[(long)gc1 * HB + j]);
    float h2 = bf2f(h[(long)gc2 * HB + j]);
    float hn = tanhf(sigm(ii) * tanhf(uu) + f1 * h1 + f2 * h2);
    if (out) out[(long)pi * HB + j] = hn;          // lv6: pi == bt, fp32 output
    else     h[(long)gp * HB + j] = f2bf(hn);
}

extern "C" void kernel_launch(void* const* d_in, const int* in_sizes, int n_in,
                              void* d_out, int out_size, void* d_ws, size_t ws_size,
                              hipStream_t stream) {
    const int*   tok = (const int*)d_in[0];
    const int*   dep = (const int*)d_in[1];
    const float* vec = (const float*)d_in[2];
    const float* q   = (const float*)d_in[3];
    const float* W   = (const float*)d_in[4];
    const float* U   = (const float*)d_in[5];
    const float* D   = (const float*)d_in[6];
    const float* b   = (const float*)d_in[7];

    char* ws = (char*)d_ws;
    size_t off = 0;
    auto alloc = [&](size_t bytes) {
        void* p = ws + off;
        off += (bytes + 255) & ~(size_t)255;
        return p;
    };
    float* qD = (float*)alloc((size_t)QQ * 768 * 4);
    u16*   vb = (u16*)alloc((size_t)VV * KEP * 2);
    u16*   Wb = (u16*)alloc((size_t)768 * KEP * 2);
    u16*   Ub = (u16*)alloc((size_t)768 * HB * 2);
    u16*   vW = (u16*)alloc((size_t)VV * 768 * 2);
    u16*   h  = (u16*)alloc((size_t)BT * NND * HB * 2);
    u16*   g  = (u16*)alloc((size_t)BT * 64 * 768 * 2);
    if (ws_size < off) return;  // ~177 MiB needed; zero output signals ws too small

    k_conv<<<(VV * (KEP / 8) + 255) / 256, 256, 0, stream>>>(vec, vb, VV, KE, KEP);
    k_conv<<<(768 * (KEP / 8) + 255) / 256, 256, 0, stream>>>(W, Wb, 768, KE, KEP);
    k_conv<<<(768 * (HB / 8) + 255) / 256, 256, 0, stream>>>(U, Ub, 768, HB, HB);
    k_qd<<<30, 256, 0, stream>>>(q, D, qD);

    // vW = (idx2vec @ W.T) as bf16, vocab-wide
    k_gemm<true><<<dim3(6, (VV + 127) / 128), 256, 0, stream>>>(
        vb, Wb, vW, VV, 768, KEP, -1, 0);

    k_leaf<<<BT * 64, 256, 0, stream>>>(tok, vW, qD, b, h);

    for (int lv = 1; lv <= 6; ++lv) {
        int pnl = 6 - lv;              // log2(parents per tree)
        int pn = 1 << pnl;
        int pstart = pn - 1;
        int cnl = pnl + 1;             // log2(children per tree)
        int cstart = (1 << cnl) - 1;
        int npT = BT * pn, ncT = BT * (1 << cnl);
        // g[children, 768] = h_child @ U.T  (A rows mapped into the tree layout)
        k_gemm<true><<<dim3(6, ncT / 128), 256, 0, stream>>>(
            h, Ub, g, ncT, 768, HB, cnl, cstart);
        k_update<<<npT, 256, 0, stream>>>(tok, dep, vW, qD, b, g, h,
                                          (lv == 6) ? (float*)d_out : nullptr,
                                          pstart, pnl);
    }
}

// Round 5
// 241.090 us; speedup vs baseline: 1.7444x; 1.0227x over previous
//
#include <hip/hip_runtime.h>

typedef unsigned short u16;
typedef u16 u16x8 __attribute__((ext_vector_type(8)));
typedef __bf16 bf16x8 __attribute__((ext_vector_type(8)));
typedef float f32x4 __attribute__((ext_vector_type(4)));

#define HB   256    // H
#define NND  127    // nodes per tree
#define BT   512    // trees (batch)
#define KE   300    // E
#define KEP  320    // E padded to 32-multiple
#define VV   50000  // vocab
#define QQ   10     // Q

#define AS1 __attribute__((address_space(1)))
#define AS3 __attribute__((address_space(3)))

__device__ __forceinline__ u16 f2bf(float f) {
    unsigned int u = __builtin_bit_cast(unsigned int, f);
    u += 0x7FFFu + ((u >> 16) & 1u);          // RNE
    return (u16)(u >> 16);
}
__device__ __forceinline__ float bf2f(u16 h) {
    unsigned int u = ((unsigned int)h) << 16;
    return __builtin_bit_cast(float, u);
}
__device__ __forceinline__ float sigm(float x) { return 1.f / (1.f + __expf(-x)); }

__device__ __forceinline__ void glds16(const u16* g, u16* l) {
    __builtin_amdgcn_global_load_lds((const AS1 void*)g, (AS3 void*)l, 16, 0, 0);
}

// ---------- fp32 -> bf16 convert with K -> Kp zero padding, u16x8 stores ----------
__global__ __launch_bounds__(256) void k_conv(const float* __restrict__ src,
                                              u16* __restrict__ dst,
                                              int rows, int K, int Kp) {
    int i = blockIdx.x * 256 + threadIdx.x;   // one 8-elem chunk per thread
    int nch = Kp >> 3;
    if (i >= rows * nch) return;
    int r = i / nch, c = (i - r * nch) * 8;
    const float* s = src + (long)r * K + c;
    u16x8 o;
#pragma unroll
    for (int e = 0; e < 8; ++e) o[e] = (c + e < K) ? f2bf(s[e]) : (u16)0;
    *(u16x8*)(dst + (long)i * 8) = o;
}

// ---------- qD = q @ D.T  (QQ x 768), fp32 ----------
__global__ __launch_bounds__(256) void k_qd(const float* __restrict__ q,
                                            const float* __restrict__ D,
                                            float* __restrict__ qD) {
    int i = blockIdx.x * 256 + threadIdx.x;
    if (i >= QQ * 768) return;
    int qi = i / 768, col = i - qi * 768;
    const float* qr = q + qi * HB;
    const float* dr = D + col * HB;
    float s = 0.f;
    for (int k = 0; k < HB; ++k) s += qr[k] * dr[k];
    qD[i] = s;
}

// ---------- bf16 NT GEMM: global_load_lds(16B), 128x128 tile, 2-phase prefetch ----------
// C[M,N] = A[M,K] * B[N,K]^T ; A,B bf16 row-major, K % 64 == 0 (nk even), N % 128 == 0.
// optional A-row map: global_row = (r>>cnlog2)*127 + cstart + (r & ((1<<cnlog2)-1))
template <bool STORE_BF16>
__global__ __launch_bounds__(256) void k_gemm(const u16* __restrict__ A,
                                              const u16* __restrict__ B,
                                              void* __restrict__ C,
                                              int M, int N, int K,
                                              int map_cnlog2, int map_cstart) {
    __shared__ u16 As[2][128 * 32];
    __shared__ u16 Bs[2][128 * 32];

    // bijective XCD-chunked swizzle (m204) on linear bid, x-inner
    int nwg = gridDim.x * gridDim.y;
    int orig = blockIdx.y * gridDim.x + blockIdx.x;
    int qq = nwg >> 3, rr = nwg & 7;
    int xcd = orig & 7, cidx = orig >> 3;
    int wg = (xcd < rr ? xcd * (qq + 1) : rr * (qq + 1) + (xcd - rr) * qq) + cidx;
    int bx = wg % gridDim.x, by = wg / gridDim.x;
    int row0 = by * 128, col0 = bx * 128;

    int t = threadIdx.x, lane = t & 63, w = t >> 6;
    int wr = w >> 1, wc = w & 1;

    // staging geometry: per wave-issue, 64 lanes x 16B = 16 rows x 32 u16
    int cof = (lane & 3) * 8;            // u16 col offset
    int rin = lane >> 2;                 // 0..15 row within issue
    int ar0 = row0 + w * 32 + rin;
    int ar1 = ar0 + 16;
    auto mapfn = [&](int r) {
        if (r > M - 1) r = M - 1;
        if (map_cnlog2 >= 0) {
            int bt = r >> map_cnlog2;
            int of = r & ((1 << map_cnlog2) - 1);
            r = bt * NND + map_cstart + of;
        }
        return r;
    };
    const u16* aS0 = A + (long)mapfn(ar0) * K + cof;
    const u16* aS1 = A + (long)mapfn(ar1) * K + cof;
    const u16* bS0 = B + (long)(col0 + w * 32 + rin) * K + cof;
    const u16* bS1 = bS0 + 16L * K;
    int dof0 = (w * 32) * 32;
    int dof1 = (w * 32 + 16) * 32;

    f32x4 acc[4][4];
#pragma unroll
    for (int m = 0; m < 4; ++m)
#pragma unroll
        for (int n = 0; n < 4; ++n) acc[m][n] = f32x4{0.f, 0.f, 0.f, 0.f};

    int arl = wr * 64 + (lane & 15);
    int brl = wc * 64 + (lane & 15);
    int kk = (lane >> 4) * 8;

    auto stage = [&](int sel, int ko) {
        glds16(aS0 + ko, &As[sel][dof0]);
        glds16(aS1 + ko, &As[sel][dof1]);
        glds16(bS0 + ko, &Bs[sel][dof0]);
        glds16(bS1 + ko, &Bs[sel][dof1]);
    };
    auto compute = [&](int sel) {
        bf16x8 af[4], bfr[4];
#pragma unroll
        for (int m = 0; m < 4; ++m)
            af[m] = *(const bf16x8*)&As[sel][(arl + m * 16) * 32 + kk];
#pragma unroll
        for (int n = 0; n < 4; ++n)
            bfr[n] = *(const bf16x8*)&Bs[sel][(brl + n * 16) * 32 + kk];
#pragma unroll
        for (int m = 0; m < 4; ++m)
#pragma unroll
            for (int n = 0; n < 4; ++n)
                acc[m][n] = __builtin_amdgcn_mfma_f32_16x16x32_bf16(af[m], bfr[n], acc[m][n], 0, 0, 0);
    };

    int nk = K >> 5;                     // always even here (10 or 8)
    stage(0, 0);
    __syncthreads();                     // drains vmcnt -> buf0 ready
    for (int kt = 0; kt < nk; kt += 2) {
        if (kt + 1 < nk) stage(1, (kt + 1) * 32);   // prefetch next into buf1
        compute(0);
        __syncthreads();                 // drains prefetch; buf1 ready, buf0 free
        if (kt + 2 < nk) stage(0, (kt + 2) * 32);   // prefetch next+1 into buf0
        compute(1);
        __syncthreads();
    }

    int crow = row0 + wr * 64 + (lane >> 4) * 4;
    int ccol = col0 + wc * 64 + (lane & 15);
#pragma unroll
    for (int m = 0; m < 4; ++m) {
#pragma unroll
        for (int n = 0; n < 4; ++n) {
#pragma unroll
            for (int j = 0; j < 4; ++j) {
                int r = crow + m * 16 + j;
                int c = ccol + n * 16;
                if (r < M) {
                    if (STORE_BF16) ((u16*)C)[(long)r * N + c] = f2bf(acc[m][n][j]);
                    else            ((float*)C)[(long)r * N + c] = acc[m][n][j];
                }
            }
        }
    }
}

// ---------- leaves: h = tanh(sigmoid(i0)*tanh(u0)) ----------
__global__ __launch_bounds__(256) void k_leaf(const int* __restrict__ tok,
                                              const u16* __restrict__ vW,
                                              const float* __restrict__ qD,
                                              const float* __restrict__ b,
                                              u16* __restrict__ h) {
    int leaf = blockIdx.x, j = threadIdx.x;
    int bt = leaf >> 6, li = leaf & 63;        // 64 leaves per tree
    int row = bt * NND + 63 + li;
    long vwb = (long)tok[row] * 768;
    float ii = bf2f(vW[vwb + 256 + j]) + qD[9 * 768 + 256 + j] + b[256 + j];
    float uu = bf2f(vW[vwb + 512 + j]) + qD[9 * 768 + 512 + j] + b[512 + j];
    h[(long)row * HB + j] = f2bf(tanhf(sigm(ii) * tanhf(uu)));
}

// ---------- per-level node update reading merged g = h_child @ U.T (bf16) ----------
// g row layout per child c (compact level order): [0:256]=f-part, [256:512]=i, [512:768]=u
__global__ __launch_bounds__(256) void k_update(const int* __restrict__ tok,
                                                const int* __restrict__ dep,
                                                const u16* __restrict__ vW,
                                                const float* __restrict__ qD,
                                                const float* __restrict__ b,
                                                const u16* __restrict__ g,
                                                u16* __restrict__ h,
                                                float* __restrict__ out,
                                                int pstart, int pnl) {
    int pi = blockIdx.x, j = threadIdx.x;
    int bt = pi >> pnl, po = pi & ((1 << pnl) - 1);
    int pl = pstart + po;
    int gp  = bt * NND + pl;
    int gc1 = bt * NND + 2 * pl + 1, gc2 = gc1 + 1;
    long cc1 = (long)((bt << (pnl + 1)) + 2 * po) * 768;  // g rows of the two children
    long cc2 = cc1 + 768;
    long vwb = (long)tok[gp] * 768;
    int d1 = dep[gc1] * 768, d2 = dep[gc2] * 768;
    float xf = bf2f(vW[vwb + j]) + b[j];
    float f1 = sigm(xf + bf2f(g[cc1 + j]) + qD[d1 + j]);
    float f2 = sigm(xf + bf2f(g[cc2 + j]) + qD[d2 + j]);
    float ii = bf2f(vW[vwb + 256 + j]) + bf2f(g[cc1 + 256 + j]) + bf2f(g[cc2 + 256 + j])
             + qD[d1 + 256 + j] + qD[d2 + 256 + j] + b[256 + j];
    float uu = bf2f(vW[vwb + 512 + j]) + bf2f(g[cc1 + 512 + j]) + bf2f(g[cc2 + 512 + j])
             + qD[d1 + 512 + j] + qD[d2 + 512 + j] + b[512 + j];
    float h1 = bf2f(h[(long)gc1 * HB + j]);
    float h2 = bf2f(h[(long)gc2 * HB + j]);
    float hn = tanhf(sigm(ii) * tanhf(uu) + f1 * h1 + f2 * h2);
    if (out) out[(long)pi * HB + j] = hn;          // lv6: pi == bt, fp32 output
    else     h[(long)gp * HB + j] = f2bf(hn);
}

extern "C" void kernel_launch(void* const* d_in, const int* in_sizes, int n_in,
                              void* d_out, int out_size, void* d_ws, size_t ws_size,
                              hipStream_t stream) {
    const int*   tok = (const int*)d_in[0];
    const int*   dep = (const int*)d_in[1];
    const float* vec = (const float*)d_in[2];
    const float* q   = (const float*)d_in[3];
    const float* W   = (const float*)d_in[4];
    const float* U   = (const float*)d_in[5];
    const float* D   = (const float*)d_in[6];
    const float* b   = (const float*)d_in[7];

    char* ws = (char*)d_ws;
    size_t off = 0;
    auto alloc = [&](size_t bytes) {
        void* p = ws + off;
        off += (bytes + 255) & ~(size_t)255;
        return p;
    };
    float* qD = (float*)alloc((size_t)QQ * 768 * 4);
    u16*   vb = (u16*)alloc((size_t)VV * KEP * 2);
    u16*   Wb = (u16*)alloc((size_t)768 * KEP * 2);
    u16*   Ub = (u16*)alloc((size_t)768 * HB * 2);
    u16*   vW = (u16*)alloc((size_t)VV * 768 * 2);
    u16*   h  = (u16*)alloc((size_t)BT * NND * HB * 2);
    u16*   g  = (u16*)alloc((size_t)BT * 64 * 768 * 2);
    if (ws_size < off) return;  // ~177 MiB needed; zero output signals ws too small

    k_conv<<<(VV * (KEP / 8) + 255) / 256, 256, 0, stream>>>(vec, vb, VV, KE, KEP);
    k_conv<<<(768 * (KEP / 8) + 255) / 256, 256, 0, stream>>>(W, Wb, 768, KE, KEP);
    k_conv<<<(768 * (HB / 8) + 255) / 256, 256, 0, stream>>>(U, Ub, 768, HB, HB);
    k_qd<<<30, 256, 0, stream>>>(q, D, qD);

    // vW = (idx2vec @ W.T) as bf16, vocab-wide
    k_gemm<true><<<dim3(6, (VV + 127) / 128), 256, 0, stream>>>(
        vb, Wb, vW, VV, 768, KEP, -1, 0);

    k_leaf<<<BT * 64, 256, 0, stream>>>(tok, vW, qD, b, h);

    for (int lv = 1; lv <= 6; ++lv) {
        int pnl = 6 - lv;              // log2(parents per tree)
        int pn = 1 << pnl;
        int pstart = pn - 1;
        int cnl = pnl + 1;             // log2(children per tree)
        int cstart = (1 << cnl) - 1;
        int npT = BT * pn, ncT = BT * (1 << cnl);
        // g[children, 768] = h_child @ U.T  (A rows mapped into the tree layout)
        k_gemm<true><<<dim3(6, ncT / 128), 256, 0, stream>>>(
            h, Ub, g, ncT, 768, HB, cnl, cstart);
        k_update<<<npT, 256, 0, stream>>>(tok, dep, vW, qD, b, g, h,
                                          (lv == 6) ? (float*)d_out : nullptr,
                                          pstart, pnl);
    }
}

// Round 6
// 236.540 us; speedup vs baseline: 1.7779x; 1.0192x over previous
//
#include <hip/hip_runtime.h>

typedef unsigned short u16;
typedef u16 u16x8 __attribute__((ext_vector_type(8)));
typedef __bf16 bf16x8 __attribute__((ext_vector_type(8)));
typedef float f32x4 __attribute__((ext_vector_type(4)));

#define HB   256    // H
#define NND  127    // nodes per tree
#define BT   512    // trees (batch)
#define KE   300    // E
#define KEP  320    // E padded to 32-multiple
#define VV   50000  // vocab
#define QQ   10     // Q

#define AS1 __attribute__((address_space(1)))
#define AS3 __attribute__((address_space(3)))

__device__ __forceinline__ u16 f2bf(float f) {
    unsigned int u = __builtin_bit_cast(unsigned int, f);
    u += 0x7FFFu + ((u >> 16) & 1u);          // RNE
    return (u16)(u >> 16);
}
__device__ __forceinline__ float bf2f(u16 h) {
    unsigned int u = ((unsigned int)h) << 16;
    return __builtin_bit_cast(float, u);
}
__device__ __forceinline__ float sigm(float x) { return 1.f / (1.f + __expf(-x)); }

__device__ __forceinline__ void glds16(const u16* g, u16* l) {
    __builtin_amdgcn_global_load_lds((const AS1 void*)g, (AS3 void*)l, 16, 0, 0);
}

// ---------- fp32 -> bf16 convert with K -> Kp zero padding, u16x8 stores ----------
__global__ __launch_bounds__(256) void k_conv(const float* __restrict__ src,
                                              u16* __restrict__ dst,
                                              int rows, int K, int Kp) {
    int i = blockIdx.x * 256 + threadIdx.x;   // one 8-elem chunk per thread
    int nch = Kp >> 3;
    if (i >= rows * nch) return;
    int r = i / nch, c = (i - r * nch) * 8;
    const float* s = src + (long)r * K + c;
    u16x8 o;
#pragma unroll
    for (int e = 0; e < 8; ++e) o[e] = (c + e < K) ? f2bf(s[e]) : (u16)0;
    *(u16x8*)(dst + (long)i * 8) = o;
}

// ---------- qD = q @ D.T  (QQ x 768), fp32 ----------
__global__ __launch_bounds__(256) void k_qd(const float* __restrict__ q,
                                            const float* __restrict__ D,
                                            float* __restrict__ qD) {
    int i = blockIdx.x * 256 + threadIdx.x;
    if (i >= QQ * 768) return;
    int qi = i / 768, col = i - qi * 768;
    const float* qr = q + qi * HB;
    const float* dr = D + col * HB;
    float s = 0.f;
    for (int k = 0; k < HB; ++k) s += qr[k] * dr[k];
    qD[i] = s;
}

// ---------- bf16 NT GEMM: global_load_lds(16B), 128x128 tile ----------
// Depth-3 pipeline, 4 LDS buffers, counted vmcnt (T4) — never drains to 0 in steady state.
// C[M,N] = A[M,K] * B[N,K]^T ; A,B bf16 row-major, K/32 = nk >= 4, N % 128 == 0.
// optional A-row map: global_row = (r>>cnlog2)*127 + cstart + (r & ((1<<cnlog2)-1))
template <bool STORE_BF16>
__global__ __launch_bounds__(256) void k_gemm(const u16* __restrict__ A,
                                              const u16* __restrict__ B,
                                              void* __restrict__ C,
                                              int M, int N, int K,
                                              int map_cnlog2, int map_cstart) {
    __shared__ u16 As[4][128 * 32];
    __shared__ u16 Bs[4][128 * 32];

    // bijective XCD-chunked swizzle (m204) on linear bid, x-inner
    int nwg = gridDim.x * gridDim.y;
    int orig = blockIdx.y * gridDim.x + blockIdx.x;
    int qq = nwg >> 3, rr = nwg & 7;
    int xcd = orig & 7, cidx = orig >> 3;
    int wg = (xcd < rr ? xcd * (qq + 1) : rr * (qq + 1) + (xcd - rr) * qq) + cidx;
    int bx = wg % gridDim.x, by = wg / gridDim.x;
    int row0 = by * 128, col0 = bx * 128;

    int t = threadIdx.x, lane = t & 63, w = t >> 6;
    int wr = w >> 1, wc = w & 1;

    // staging geometry: per wave-issue, 64 lanes x 16B = 16 rows x 32 u16
    int cof = (lane & 3) * 8;            // u16 col offset
    int rin = lane >> 2;                 // 0..15 row within issue
    int ar0 = row0 + w * 32 + rin;
    int ar1 = ar0 + 16;
    auto mapfn = [&](int r) {
        if (r > M - 1) r = M - 1;
        if (map_cnlog2 >= 0) {
            int bt = r >> map_cnlog2;
            int of = r & ((1 << map_cnlog2) - 1);
            r = bt * NND + map_cstart + of;
        }
        return r;
    };
    const u16* aS0 = A + (long)mapfn(ar0) * K + cof;
    const u16* aS1 = A + (long)mapfn(ar1) * K + cof;
    const u16* bS0 = B + (long)(col0 + w * 32 + rin) * K + cof;
    const u16* bS1 = bS0 + 16L * K;
    int dof0 = (w * 32) * 32;
    int dof1 = (w * 32 + 16) * 32;

    f32x4 acc[4][4];
#pragma unroll
    for (int m = 0; m < 4; ++m)
#pragma unroll
        for (int n = 0; n < 4; ++n) acc[m][n] = f32x4{0.f, 0.f, 0.f, 0.f};

    int arl = wr * 64 + (lane & 15);
    int brl = wc * 64 + (lane & 15);
    int kk = (lane >> 4) * 8;

    auto stage = [&](int sel, int ko) {
        glds16(aS0 + ko, &As[sel][dof0]);
        glds16(aS1 + ko, &As[sel][dof1]);
        glds16(bS0 + ko, &Bs[sel][dof0]);
        glds16(bS1 + ko, &Bs[sel][dof1]);
    };
    auto compute = [&](int sel) {
        bf16x8 af[4], bfr[4];
#pragma unroll
        for (int m = 0; m < 4; ++m)
            af[m] = *(const bf16x8*)&As[sel][(arl + m * 16) * 32 + kk];
#pragma unroll
        for (int n = 0; n < 4; ++n)
            bfr[n] = *(const bf16x8*)&Bs[sel][(brl + n * 16) * 32 + kk];
#pragma unroll
        for (int m = 0; m < 4; ++m)
#pragma unroll
            for (int n = 0; n < 4; ++n)
                acc[m][n] = __builtin_amdgcn_mfma_f32_16x16x32_bf16(af[m], bfr[n], acc[m][n], 0, 0, 0);
    };

    int nk = K >> 5;                     // 8 or 10 here (>= 4 required)
    stage(0, 0); stage(1, 32); stage(2, 64);     // 12 loads/wave in flight
    for (int kt = 0; kt < nk - 3; ++kt) {
        // oldest stage (kt) complete; stages kt+1, kt+2 stay in flight
        asm volatile("s_waitcnt vmcnt(8)" ::: "memory");
        __builtin_amdgcn_s_barrier();
        __builtin_amdgcn_sched_barrier(0);
        compute(kt & 3);
        stage((kt + 3) & 3, (kt + 3) * 32);      // overwrites buf read at iter kt-1 (safe past barrier)
    }
    // tail: 3 remaining buffers, outstanding counts 12 -> 8 -> 4
    asm volatile("s_waitcnt vmcnt(8)" ::: "memory");
    __builtin_amdgcn_s_barrier();
    __builtin_amdgcn_sched_barrier(0);
    compute((nk - 3) & 3);
    asm volatile("s_waitcnt vmcnt(4)" ::: "memory");
    __builtin_amdgcn_s_barrier();
    __builtin_amdgcn_sched_barrier(0);
    compute((nk - 2) & 3);
    asm volatile("s_waitcnt vmcnt(0)" ::: "memory");
    __builtin_amdgcn_s_barrier();
    __builtin_amdgcn_sched_barrier(0);
    compute((nk - 1) & 3);

    int crow = row0 + wr * 64 + (lane >> 4) * 4;
    int ccol = col0 + wc * 64 + (lane & 15);
#pragma unroll
    for (int m = 0; m < 4; ++m) {
#pragma unroll
        for (int n = 0; n < 4; ++n) {
#pragma unroll
            for (int j = 0; j < 4; ++j) {
                int r = crow + m * 16 + j;
                int c = ccol + n * 16;
                if (r < M) {
                    if (STORE_BF16) ((u16*)C)[(long)r * N + c] = f2bf(acc[m][n][j]);
                    else            ((float*)C)[(long)r * N + c] = acc[m][n][j];
                }
            }
        }
    }
}

// ---------- leaves: h = tanh(sigmoid(i0)*tanh(u0)) ----------
__global__ __launch_bounds__(256) void k_leaf(const int* __restrict__ tok,
                                              const u16* __restrict__ vW,
                                              const float* __restrict__ qD,
                                              const float* __restrict__ b,
                                              u16* __restrict__ h) {
    int leaf = blockIdx.x, j = threadIdx.x;
    int bt = leaf >> 6, li = leaf & 63;        // 64 leaves per tree
    int row = bt * NND + 63 + li;
    long vwb = (long)tok[row] * 768;
    float ii = bf2f(vW[vwb + 256 + j]) + qD[9 * 768 + 256 + j] + b[256 + j];
    float uu = bf2f(vW[vwb + 512 + j]) + qD[9 * 768 + 512 + j] + b[512 + j];
    h[(long)row * HB + j] = f2bf(tanhf(sigm(ii) * tanhf(uu)));
}

// ---------- per-level node update reading merged g = h_child @ U.T (bf16) ----------
// g row layout per child c (compact level order): [0:256]=f-part, [256:512]=i, [512:768]=u
__global__ __launch_bounds__(256) void k_update(const int* __restrict__ tok,
                                                const int* __restrict__ dep,
                                                const u16* __restrict__ vW,
                                                const float* __restrict__ qD,
                                                const float* __restrict__ b,
                                                const u16* __restrict__ g,
                                                u16* __restrict__ h,
                                                float* __restrict__ out,
                                                int pstart, int pnl) {
    int pi = blockIdx.x, j = threadIdx.x;
    int bt = pi >> pnl, po = pi & ((1 << pnl) - 1);
    int pl = pstart + po;
    int gp  = bt * NND + pl;
    int gc1 = bt * NND + 2 * pl + 1, gc2 = gc1 + 1;
    long cc1 = (long)((bt << (pnl + 1)) + 2 * po) * 768;  // g rows of the two children
    long cc2 = cc1 + 768;
    long vwb = (long)tok[gp] * 768;
    int d1 = dep[gc1] * 768, d2 = dep[gc2] * 768;
    float xf = bf2f(vW[vwb + j]) + b[j];
    float f1 = sigm(xf + bf2f(g[cc1 + j]) + qD[d1 + j]);
    float f2 = sigm(xf + bf2f(g[cc2 + j]) + qD[d2 + j]);
    float ii = bf2f(vW[vwb + 256 + j]) + bf2f(g[cc1 + 256 + j]) + bf2f(g[cc2 + 256 + j])
             + qD[d1 + 256 + j] + qD[d2 + 256 + j] + b[256 + j];
    float uu = bf2f(vW[vwb + 512 + j]) + bf2f(g[cc1 + 512 + j]) + bf2f(g[cc2 + 512 + j])
             + qD[d1 + 512 + j] + qD[d2 + 512 + j] + b[512 + j];
    float h1 = bf2f(h[(long)gc1 * HB + j]);
    float h2 = bf2f(h[(long)gc2 * HB + j]);
    float hn = tanhf(sigm(ii) * tanhf(uu) + f1 * h1 + f2 * h2);
    if (out) out[(long)pi * HB + j] = hn;          // lv6: pi == bt, fp32 output
    else     h[(long)gp * HB + j] = f2bf(hn);
}

extern "C" void kernel_launch(void* const* d_in, const int* in_sizes, int n_in,
                              void* d_out, int out_size, void* d_ws, size_t ws_size,
                              hipStream_t stream) {
    const int*   tok = (const int*)d_in[0];
    const int*   dep = (const int*)d_in[1];
    const float* vec = (const float*)d_in[2];
    const float* q   = (const float*)d_in[3];
    const float* W   = (const float*)d_in[4];
    const float* U   = (const float*)d_in[5];
    const float* D   = (const float*)d_in[6];
    const float* b   = (const float*)d_in[7];

    char* ws = (char*)d_ws;
    size_t off = 0;
    auto alloc = [&](size_t bytes) {
        void* p = ws + off;
        off += (bytes + 255) & ~(size_t)255;
        return p;
    };
    float* qD = (float*)alloc((size_t)QQ * 768 * 4);
    u16*   vb = (u16*)alloc((size_t)VV * KEP * 2);
    u16*   Wb = (u16*)alloc((size_t)768 * KEP * 2);
    u16*   Ub = (u16*)alloc((size_t)768 * HB * 2);
    u16*   vW = (u16*)alloc((size_t)VV * 768 * 2);
    u16*   h  = (u16*)alloc((size_t)BT * NND * HB * 2);
    u16*   g  = (u16*)alloc((size_t)BT * 64 * 768 * 2);
    if (ws_size < off) return;  // ~177 MiB needed; zero output signals ws too small

    k_conv<<<(VV * (KEP / 8) + 255) / 256, 256, 0, stream>>>(vec, vb, VV, KE, KEP);
    k_conv<<<(768 * (KEP / 8) + 255) / 256, 256, 0, stream>>>(W, Wb, 768, KE, KEP);
    k_conv<<<(768 * (HB / 8) + 255) / 256, 256, 0, stream>>>(U, Ub, 768, HB, HB);
    k_qd<<<30, 256, 0, stream>>>(q, D, qD);

    // vW = (idx2vec @ W.T) as bf16, vocab-wide
    k_gemm<true><<<dim3(6, (VV + 127) / 128), 256, 0, stream>>>(
        vb, Wb, vW, VV, 768, KEP, -1, 0);

    k_leaf<<<BT * 64, 256, 0, stream>>>(tok, vW, qD, b, h);

    for (int lv = 1; lv <= 6; ++lv) {
        int pnl = 6 - lv;              // log2(parents per tree)
        int pn = 1 << pnl;
        int pstart = pn - 1;
        int cnl = pnl + 1;             // log2(children per tree)
        int cstart = (1 << cnl) - 1;
        int npT = BT * pn, ncT = BT * (1 << cnl);
        // g[children, 768] = h_child @ U.T  (A rows mapped into the tree layout)
        k_gemm<true><<<dim3(6, ncT / 128), 256, 0, stream>>>(
            h, Ub, g, ncT, 768, HB, cnl, cstart);
        k_update<<<npT, 256, 0, stream>>>(tok, dep, vW, qD, b, g, h,
                                          (lv == 6) ? (float*)d_out : nullptr,
                                          pstart, pnl);
    }
}